// Round 1
// baseline (605.472 us; speedup 1.0000x reference)
//
#include <hip/hip_runtime.h>
#include <cmath>

#define BB 8
#define SS 8192
#define DD 384
#define CH 64
#define NC 128

typedef _Float16 h8_t __attribute__((ext_vector_type(8)));
typedef _Float16 h4_t __attribute__((ext_vector_type(4)));
typedef float f32x4 __attribute__((ext_vector_type(4)));

// ---------------------------------------------------------------- K1: stats
// per (b,n): chunk row norms, xbar, kmean, u = xbar-kmean, gate -> A,B
// also: x -> f16 cast (XF), M0 -> f16 (first 64 WGs), zero PHI2 slot.
__global__ __launch_bounds__(512) void k1_stats(
    const float* __restrict__ x, const float* __restrict__ M0,
    const float* __restrict__ eta_raw, const float* __restrict__ alpha_raw,
    const float* __restrict__ gate_w, const float* __restrict__ gate_b,
    _Float16* __restrict__ XF, float* __restrict__ U, float* __restrict__ K32,
    _Float16* __restrict__ KF, float* __restrict__ AB, float* __restrict__ PHI2,
    _Float16* __restrict__ M0H)
{
    __shared__ float ch[CH][DD];
    __shared__ float rinv[CH];
    __shared__ float red[8];
    const int wg = blockIdx.x, tid = threadIdx.x;
    const int b = wg >> 7, n = wg & 127;
    const int lane = tid & 63, wid = tid >> 6;

    if (wg < 64) {  // cast M0 -> f16 (64*2304 = 147456 elems)
        for (int i = tid; i < 2304; i += 512) {
            int idx = wg * 2304 + i;
            M0H[idx] = (_Float16)M0[idx];
        }
    }
    if (tid == 0) PHI2[wg] = 0.f;

    const size_t chunk_off = (size_t)(b * SS + n * CH) * DD;
    const float4* __restrict__ xin = (const float4*)(x + chunk_off);
    h4_t* __restrict__ xf = (h4_t*)(XF + chunk_off);
    for (int i = tid; i < CH * DD / 4; i += 512) {
        float4 v = xin[i];
        int base = i * 4, r = base / DD, c = base % DD;
        ch[r][c] = v.x; ch[r][c + 1] = v.y; ch[r][c + 2] = v.z; ch[r][c + 3] = v.w;
        h4_t h; h[0] = (_Float16)v.x; h[1] = (_Float16)v.y;
        h[2] = (_Float16)v.z; h[3] = (_Float16)v.w;
        xf[i] = h;
    }
    __syncthreads();

    // row norms: 8 waves x 8 rows
    for (int r = wid * 8; r < wid * 8 + 8; ++r) {
        float s = 0.f;
        for (int t = 0; t < 6; ++t) { float v = ch[r][lane + 64 * t]; s += v * v; }
        for (int off = 32; off; off >>= 1) s += __shfl_xor(s, off);
        if (lane == 0) rinv[r] = 1.f / fmaxf(sqrtf(s), 1e-5f);
    }
    __syncthreads();

    float gpart = 0.f;
    for (int d = tid; d < DD; d += 512) {
        float xa = 0.f, km = 0.f;
        for (int c = 0; c < CH; ++c) { float v = ch[c][d]; xa += v; km += v * rinv[c]; }
        xa *= (1.f / 64.f); km *= (1.f / 64.f);
        int o = (b * NC + n) * DD + d;
        U[o] = xa - km; K32[o] = km; KF[o] = (_Float16)km;
        gpart += km * gate_w[d];
    }
    for (int off = 32; off; off >>= 1) gpart += __shfl_xor(gpart, off);
    if (lane == 0) red[wid] = gpart;
    __syncthreads();
    if (tid == 0) {
        float gsum = 0.f;
        for (int i = 0; i < 8; ++i) gsum += red[i];
        float g = 1.f / (1.f + expf(-(gsum + gate_b[0])));
        float eta = 0.2f / (1.f + expf(-eta_raw[0]));
        float alpha = 0.5f + 0.5f / (1.f + expf(-alpha_raw[0]));
        AB[wg * 2 + 0] = g * alpha + 1.f - g;   // A_n
        AB[wg * 2 + 1] = g * eta;               // B_n
    }
}

// ------------------------------------------------------------- K2: row scan
// 384 WGs (8 batches x 48), 4 waves/WG, 2 rows/wave. Row o of Mtilde evolves:
// m <- A*m + B*(m.u)*k.  Byproducts: VT[b][n][o] = m.u (pre-update),
// PHI2[b][n] += ||m||^2 (post-update), final rows -> MFW.
__global__ __launch_bounds__(256) void k2_rowscan(
    const float* __restrict__ M0, const float* __restrict__ U,
    const float* __restrict__ K32, const float* __restrict__ AB,
    float* __restrict__ PHI2, float* __restrict__ VT, float* __restrict__ MFW)
{
    const int b = blockIdx.x / 48, wg = blockIdx.x % 48;
    const int tid = threadIdx.x, lane = tid & 63, wid = tid >> 6;
    const int o0 = wg * 8 + wid * 2;
    float m0[6], m1[6];
    for (int t = 0; t < 6; ++t) {
        m0[t] = M0[(size_t)o0 * DD + lane + 64 * t];
        m1[t] = M0[(size_t)(o0 + 1) * DD + lane + 64 * t];
    }
    const float* __restrict__ Ub = U + (size_t)b * NC * DD;
    const float* __restrict__ Kb = K32 + (size_t)b * NC * DD;
    for (int n = 0; n < NC; ++n) {
        float u[6], kv[6];
        for (int t = 0; t < 6; ++t) {
            u[t] = Ub[n * DD + lane + 64 * t];
            kv[t] = Kb[n * DD + lane + 64 * t];
        }
        float d0 = 0.f, d1 = 0.f;
        for (int t = 0; t < 6; ++t) { d0 += m0[t] * u[t]; d1 += m1[t] * u[t]; }
        for (int off = 32; off; off >>= 1) {
            d0 += __shfl_xor(d0, off); d1 += __shfl_xor(d1, off);
        }
        float A = AB[(b * NC + n) * 2], Bc = AB[(b * NC + n) * 2 + 1];
        if (lane == 0) {
            VT[(size_t)(b * NC + n) * DD + o0] = d0;
            VT[(size_t)(b * NC + n) * DD + o0 + 1] = d1;
        }
        float c0 = Bc * d0, c1 = Bc * d1, p = 0.f;
        for (int t = 0; t < 6; ++t) {
            m0[t] = A * m0[t] + c0 * kv[t];
            m1[t] = A * m1[t] + c1 * kv[t];
            p += m0[t] * m0[t] + m1[t] * m1[t];
        }
        for (int off = 32; off; off >>= 1) p += __shfl_xor(p, off);
        if (lane == 0) atomicAdd(&PHI2[b * NC + n], p);
    }
    for (int t = 0; t < 6; ++t) {
        MFW[((size_t)b * DD + o0) * DD + lane + 64 * t] = m0[t];
        MFW[((size_t)b * DD + o0 + 1) * DD + lane + 64 * t] = m1[t];
    }
}

// ------------------------------------------------------- K3: scalar scan + Wt
// per batch: kappa/rho/s recursion -> SIG[n] = rho_n*kappa_n, tau[n] = B/kappa_{n+1},
// FRHO = rho_final; then Wt[b][o][j] = f16(tau_j * VT[b][j][o]).
__global__ __launch_bounds__(256) void k3_scan(
    const float* __restrict__ AB, const float* __restrict__ PHI2,
    const float* __restrict__ VT, float* __restrict__ SIG,
    float* __restrict__ FRHO, _Float16* __restrict__ WT)
{
    const int b = blockIdx.x, tid = threadIdx.x;
    __shared__ float sA[NC], sB[NC], sP[NC], tau[NC], sig[NC];
    for (int i = tid; i < NC; i += 256) {
        sA[i] = AB[(b * NC + i) * 2];
        sB[i] = AB[(b * NC + i) * 2 + 1];
        sP[i] = PHI2[b * NC + i];
    }
    __syncthreads();
    if (tid == 0) {
        float kap = 1.f, rho = 1.f;
        for (int i = 0; i < NC; ++i) {
            float kap1 = kap * sA[i];
            sig[i] = rho * kap;
            tau[i] = sB[i] / kap1;
            float s = fminf(30.f / (rho * sqrtf(sP[i]) + 1e-6f), 1.f);
            rho *= s; kap = kap1;
        }
        FRHO[b] = rho;
    }
    __syncthreads();
    for (int i = tid; i < NC; i += 256) SIG[b * NC + i] = sig[i];
    for (int i = tid; i < NC * DD; i += 256) {
        int j = i / DD, o = i - j * DD;
        WT[((size_t)b * DD + o) * NC + j] =
            (_Float16)(tau[j] * VT[(size_t)(b * NC + j) * DD + o]);
    }
}

// ------------------------------------------------------------ K4: output GEMM
// per (b,n) WG: out_n = sig_n * [chunk_n @ M0^T + (chunk_n @ K_{<n}) @ Wt^T]
// f16 MFMA 16x16x32, fp32 accum. Last 64 WGs write M_fin = rho_128 * MFW.
__global__ __launch_bounds__(256) void k4_out(
    const _Float16* __restrict__ XF, const _Float16* __restrict__ M0H,
    const _Float16* __restrict__ KF, const _Float16* __restrict__ WT,
    const float* __restrict__ SIG, const float* __restrict__ FRHO,
    const float* __restrict__ MFW, float* __restrict__ out)
{
    if (blockIdx.x >= BB * NC) {  // M_fin tail
        const int w = blockIdx.x - BB * NC;
        const float4* __restrict__ src = (const float4*)MFW;
        float4* __restrict__ dst = (float4*)(out + (size_t)BB * SS * DD);
        const int per = (BB * DD * DD / 4) / 64;  // 4608
        for (int i = threadIdx.x; i < per; i += 256) {
            int idx = w * per + i;
            int b = (idx * 4) / (DD * DD);
            float r = FRHO[b];
            float4 v = src[idx];
            v.x *= r; v.y *= r; v.z *= r; v.w *= r;
            dst[idx] = v;
        }
        return;
    }
    const int b = blockIdx.x >> 7, n = blockIdx.x & 127;
    __shared__ _Float16 lds[CH * 392];  // chunk[64][392] then reused as S[64][136]
    const int tid = threadIdx.x, lane = tid & 63, w = tid >> 6;
    const int q = lane >> 4, l15 = lane & 15;

    const size_t chunk_off = (size_t)(b * SS + n * CH) * DD;
    {
        const h4_t* __restrict__ xs = (const h4_t*)(XF + chunk_off);
        for (int i = tid; i < CH * DD / 4; i += 256) {
            int base = i * 4, r = base / DD, c = base % DD;
            *(h4_t*)&lds[r * 392 + c] = xs[i];
        }
    }
    __syncthreads();

    f32x4 acc[4][6];
    for (int mi = 0; mi < 4; ++mi)
        for (int nj = 0; nj < 6; ++nj) acc[mi][nj] = (f32x4){0.f, 0.f, 0.f, 0.f};

    // term1: chunk @ M0^T   (K = 384, B streamed from L2-resident M0H)
    for (int kd = 0; kd < 12; ++kd) {
        h8_t af[4];
        for (int mi = 0; mi < 4; ++mi)
            af[mi] = *(const h8_t*)&lds[(mi * 16 + l15) * 392 + kd * 32 + q * 8];
        h8_t bf[6];
        for (int nj = 0; nj < 6; ++nj) {
            int o = w * 96 + nj * 16 + l15;
            bf[nj] = *(const h8_t*)&M0H[(size_t)o * DD + kd * 32 + q * 8];
        }
        for (int mi = 0; mi < 4; ++mi)
            for (int nj = 0; nj < 6; ++nj)
                acc[mi][nj] = __builtin_amdgcn_mfma_f32_16x16x32_f16(
                    af[mi], bf[nj], acc[mi][nj], 0, 0, 0);
    }

    // scores S = chunk @ K^T (only j-blocks < n), wave w owns j in [32w,32w+32)
    const int nb = (n + 31) >> 5;
    const bool sact = (w * 32 < n);
    f32x4 sacc[4][2];
    if (sact) {
        for (int mi = 0; mi < 4; ++mi)
            for (int nj = 0; nj < 2; ++nj) sacc[mi][nj] = (f32x4){0.f, 0.f, 0.f, 0.f};
        for (int kd = 0; kd < 12; ++kd) {
            h8_t af[4];
            for (int mi = 0; mi < 4; ++mi)
                af[mi] = *(const h8_t*)&lds[(mi * 16 + l15) * 392 + kd * 32 + q * 8];
            h8_t bf[2];
            for (int nj = 0; nj < 2; ++nj) {
                int j = w * 32 + nj * 16 + l15;
                bf[nj] = *(const h8_t*)&KF[((size_t)(b * NC) + j) * DD + kd * 32 + q * 8];
            }
            for (int mi = 0; mi < 4; ++mi)
                for (int nj = 0; nj < 2; ++nj)
                    sacc[mi][nj] = __builtin_amdgcn_mfma_f32_16x16x32_f16(
                        af[mi], bf[nj], sacc[mi][nj], 0, 0, 0);
        }
    }
    __syncthreads();  // everyone done reading chunk from lds
    if (sact) {       // write masked S (f16) into reused lds, stride 136
        for (int mi = 0; mi < 4; ++mi)
            for (int nj = 0; nj < 2; ++nj)
                for (int r = 0; r < 4; ++r) {
                    int c = mi * 16 + q * 4 + r, j = w * 32 + nj * 16 + l15;
                    lds[c * 136 + j] = (_Float16)((j < n) ? sacc[mi][nj][r] : 0.f);
                }
    }
    __syncthreads();

    // PV: acc += S @ Wt^T   (K = 32*nb)
    for (int kb = 0; kb < nb; ++kb) {
        h8_t af[4];
        for (int mi = 0; mi < 4; ++mi)
            af[mi] = *(const h8_t*)&lds[(mi * 16 + l15) * 136 + kb * 32 + q * 8];
        h8_t bf[6];
        for (int nj = 0; nj < 6; ++nj) {
            int o = w * 96 + nj * 16 + l15;
            bf[nj] = *(const h8_t*)&WT[((size_t)(b * DD) + o) * NC + kb * 32 + q * 8];
        }
        for (int mi = 0; mi < 4; ++mi)
            for (int nj = 0; nj < 6; ++nj)
                acc[mi][nj] = __builtin_amdgcn_mfma_f32_16x16x32_f16(
                    af[mi], bf[nj], acc[mi][nj], 0, 0, 0);
    }

    const float sg = SIG[b * NC + n];
    for (int mi = 0; mi < 4; ++mi)
        for (int nj = 0; nj < 6; ++nj)
            for (int r = 0; r < 4; ++r) {
                int c = mi * 16 + q * 4 + r, o = w * 96 + nj * 16 + l15;
                out[chunk_off + (size_t)c * DD + o] = sg * acc[mi][nj][r];
            }
}

// ---------------------------------------------------------------- launch
extern "C" void kernel_launch(void* const* d_in, const int* in_sizes, int n_in,
                              void* d_out, int out_size, void* d_ws, size_t ws_size,
                              hipStream_t stream) {
    (void)in_sizes; (void)n_in; (void)out_size; (void)ws_size;
    const float* x         = (const float*)d_in[0];
    const float* M0        = (const float*)d_in[1];
    const float* eta_raw   = (const float*)d_in[2];
    const float* alpha_raw = (const float*)d_in[3];
    const float* gate_w    = (const float*)d_in[4];
    const float* gate_b    = (const float*)d_in[5];
    float* out = (float*)d_out;
    char* ws = (char*)d_ws;

    _Float16* XF  = (_Float16*)(ws);                 // 50,331,648 B
    float*    U   = (float*)(ws + 50331648);         //  1,572,864
    float*    K32 = (float*)(ws + 51904512);         //  1,572,864
    _Float16* KF  = (_Float16*)(ws + 53477376);      //    786,432
    float*    AB  = (float*)(ws + 54263808);         //      8,192
    float*    PHI2= (float*)(ws + 54272000);         //      4,096
    float*    VT  = (float*)(ws + 54276096);         //  1,572,864
    float*    SIG = (float*)(ws + 55848960);         //      4,096
    float*    FRHO= (float*)(ws + 55853056);         //        256
    _Float16* WT  = (_Float16*)(ws + 55853312);      //    786,432
    float*    MFW = (float*)(ws + 56639744);         //  4,718,592
    _Float16* M0H = (_Float16*)(ws + 61358336);      //    294,912  (end ~61.7 MB)

    k1_stats<<<dim3(BB * NC), dim3(512), 0, stream>>>(
        x, M0, eta_raw, alpha_raw, gate_w, gate_b, XF, U, K32, KF, AB, PHI2, M0H);
    k2_rowscan<<<dim3(BB * 48), dim3(256), 0, stream>>>(
        M0, U, K32, AB, PHI2, VT, MFW);
    k3_scan<<<dim3(BB), dim3(256), 0, stream>>>(AB, PHI2, VT, SIG, FRHO, WT);
    k4_out<<<dim3(BB * NC + 64), dim3(256), 0, stream>>>(
        XF, M0H, KF, WT, SIG, FRHO, MFW, out);
}

// Round 2
// 492.355 us; speedup vs baseline: 1.2297x; 1.2297x over previous
//
#include <hip/hip_runtime.h>
#include <cmath>

#define BB 8
#define SS 8192
#define DD 384
#define CH 64
#define NC 128

typedef _Float16 h8_t __attribute__((ext_vector_type(8)));
typedef _Float16 h4_t __attribute__((ext_vector_type(4)));
typedef float f32x4 __attribute__((ext_vector_type(4)));

#define MFMA __builtin_amdgcn_mfma_f32_16x16x32_f16

// ---------------------------------------------------------------- K1: stats
// per (b,n): row norms, kmean, u = xbar-kmean, gate -> A,B, tau=B/A, skk=|k|^2
// also: x -> f16 (XF), M0 -> f16 (first 64 WGs).
__global__ __launch_bounds__(512) void k1_stats(
    const float* __restrict__ x, const float* __restrict__ M0,
    const float* __restrict__ eta_raw, const float* __restrict__ alpha_raw,
    const float* __restrict__ gate_w, const float* __restrict__ gate_b,
    _Float16* __restrict__ XF, _Float16* __restrict__ UF,
    _Float16* __restrict__ KF, float* __restrict__ AB, float* __restrict__ TAB,
    float* __restrict__ SKK, _Float16* __restrict__ M0H)
{
    __shared__ float ch[CH][DD];
    __shared__ float rinv[CH];
    __shared__ float redg[8], redk[8];
    const int wg = blockIdx.x, tid = threadIdx.x;
    const int b = wg >> 7, n = wg & 127;
    const int lane = tid & 63, wid = tid >> 6;

    if (wg < 64) {  // cast M0 -> f16
        for (int i = tid; i < 2304; i += 512) {
            int idx = wg * 2304 + i;
            M0H[idx] = (_Float16)M0[idx];
        }
    }

    const size_t chunk_off = (size_t)(b * SS + n * CH) * DD;
    const float4* __restrict__ xin = (const float4*)(x + chunk_off);
    h4_t* __restrict__ xf = (h4_t*)(XF + chunk_off);
    for (int i = tid; i < CH * DD / 4; i += 512) {
        float4 v = xin[i];
        int base = i * 4, r = base / DD, c = base % DD;
        ch[r][c] = v.x; ch[r][c + 1] = v.y; ch[r][c + 2] = v.z; ch[r][c + 3] = v.w;
        h4_t h; h[0] = (_Float16)v.x; h[1] = (_Float16)v.y;
        h[2] = (_Float16)v.z; h[3] = (_Float16)v.w;
        xf[i] = h;
    }
    __syncthreads();

    for (int r = wid * 8; r < wid * 8 + 8; ++r) {
        float s = 0.f;
        for (int t = 0; t < 6; ++t) { float v = ch[r][lane + 64 * t]; s += v * v; }
        for (int off = 32; off; off >>= 1) s += __shfl_xor(s, off);
        if (lane == 0) rinv[r] = 1.f / fmaxf(sqrtf(s), 1e-5f);
    }
    __syncthreads();

    float gpart = 0.f, skkp = 0.f;
    for (int d = tid; d < DD; d += 512) {
        float xa = 0.f, km = 0.f;
        for (int c = 0; c < CH; ++c) { float v = ch[c][d]; xa += v; km += v * rinv[c]; }
        xa *= (1.f / 64.f); km *= (1.f / 64.f);
        int o = (b * NC + n) * DD + d;
        UF[o] = (_Float16)(xa - km);
        KF[o] = (_Float16)km;
        gpart += km * gate_w[d];
        skkp += km * km;
    }
    for (int off = 32; off; off >>= 1) {
        gpart += __shfl_xor(gpart, off);
        skkp += __shfl_xor(skkp, off);
    }
    if (lane == 0) { redg[wid] = gpart; redk[wid] = skkp; }
    __syncthreads();
    if (tid == 0) {
        float gsum = 0.f, ks = 0.f;
        for (int i = 0; i < 8; ++i) { gsum += redg[i]; ks += redk[i]; }
        float g = 1.f / (1.f + expf(-(gsum + gate_b[0])));
        float eta = 0.2f / (1.f + expf(-eta_raw[0]));
        float alpha = 0.5f + 0.5f / (1.f + expf(-alpha_raw[0]));
        float A = g * alpha + 1.f - g;
        float Bc = g * eta;
        AB[wg * 2 + 0] = A;
        AB[wg * 2 + 1] = Bc;
        TAB[wg] = Bc / A;       // tau_hat_n
        SKK[wg] = ks;           // ||kbar_n||^2
    }
}

// ------------------------------------------------------- Kgram: GT, HT
// GT[n][j] = (j<n) ? tau_j * (k_j . u_n) : 0 ;  HT likewise with (k_j . k_n).
__global__ __launch_bounds__(256) void k_gram(
    const _Float16* __restrict__ KF, const _Float16* __restrict__ UF,
    const float* __restrict__ TAB, _Float16* __restrict__ GT,
    _Float16* __restrict__ HT)
{
    const int b = blockIdx.x;
    const int tid = threadIdx.x, lane = tid & 63, w = tid >> 6;
    const int q = lane >> 4, l15 = lane & 15;
    const _Float16* Kb = KF + (size_t)b * NC * DD;
    const _Float16* Ub = UF + (size_t)b * NC * DD;
    for (int pass = 0; pass < 2; ++pass) {
        const _Float16* Bm = pass ? Kb : Ub;
        _Float16* Out = pass ? HT : GT;
        f32x4 acc[2][8];
        for (int mt = 0; mt < 2; ++mt)
            for (int nt = 0; nt < 8; ++nt) acc[mt][nt] = (f32x4){0.f, 0.f, 0.f, 0.f};
        for (int kd = 0; kd < 12; ++kd) {
            h8_t af[2];
            for (int mt = 0; mt < 2; ++mt) {
                int j = w * 32 + mt * 16 + l15;
                af[mt] = *(const h8_t*)&Kb[(size_t)j * DD + kd * 32 + q * 8];
            }
            h8_t bf[8];
            for (int nt = 0; nt < 8; ++nt) {
                int nn = nt * 16 + l15;
                bf[nt] = *(const h8_t*)&Bm[(size_t)nn * DD + kd * 32 + q * 8];
            }
            for (int mt = 0; mt < 2; ++mt)
                for (int nt = 0; nt < 8; ++nt)
                    acc[mt][nt] = MFMA(af[mt], bf[nt], acc[mt][nt], 0, 0, 0);
        }
        for (int mt = 0; mt < 2; ++mt)
            for (int nt = 0; nt < 8; ++nt)
                for (int r = 0; r < 4; ++r) {
                    int j = w * 32 + mt * 16 + q * 4 + r;
                    int nn = nt * 16 + l15;
                    float v = (j < nn) ? TAB[b * NC + j] * acc[mt][nt][r] : 0.f;
                    Out[((size_t)b * NC + nn) * NC + j] = (_Float16)v;
                }
    }
}

// ------------------------------------------------------- Kv0: V0T = U @ M0^T
__global__ __launch_bounds__(256) void k_v0(
    const _Float16* __restrict__ UF, const _Float16* __restrict__ M0H,
    _Float16* __restrict__ V0T)
{
    const int b = blockIdx.x / 3, ob = blockIdx.x % 3;
    const int tid = threadIdx.x, lane = tid & 63, w = tid >> 6;
    const int q = lane >> 4, l15 = lane & 15;
    f32x4 acc[2][8];
    for (int mt = 0; mt < 2; ++mt)
        for (int ot = 0; ot < 8; ++ot) acc[mt][ot] = (f32x4){0.f, 0.f, 0.f, 0.f};
    for (int kd = 0; kd < 12; ++kd) {
        h8_t af[2];
        for (int mt = 0; mt < 2; ++mt) {
            int n = w * 32 + mt * 16 + l15;
            af[mt] = *(const h8_t*)&UF[((size_t)b * NC + n) * DD + kd * 32 + q * 8];
        }
        h8_t bf[8];
        for (int ot = 0; ot < 8; ++ot) {
            int o = ob * 128 + ot * 16 + l15;
            bf[ot] = *(const h8_t*)&M0H[(size_t)o * DD + kd * 32 + q * 8];
        }
        for (int mt = 0; mt < 2; ++mt)
            for (int ot = 0; ot < 8; ++ot)
                acc[mt][ot] = MFMA(af[mt], bf[ot], acc[mt][ot], 0, 0, 0);
    }
    for (int mt = 0; mt < 2; ++mt)
        for (int ot = 0; ot < 8; ++ot)
            for (int r = 0; r < 4; ++r) {
                int n = w * 32 + mt * 16 + q * 4 + r;
                int o = ob * 128 + ot * 16 + l15;
                V0T[((size_t)b * NC + n) * DD + o] = (_Float16)acc[mt][ot][r];
            }
}

// ------------------------------------------------------- Kchain: DST = V0T + GT @ SRC
__global__ __launch_bounds__(256) void k_chain(
    const _Float16* __restrict__ SRC, const _Float16* __restrict__ V0T,
    const _Float16* __restrict__ GT, _Float16* __restrict__ DST)
{
    __shared__ _Float16 T[128 * 136];  // T[o_local][j] = SRC[j][ob*128+o]
    const int b = blockIdx.x / 3, ob = blockIdx.x % 3;
    const int tid = threadIdx.x, lane = tid & 63, w = tid >> 6;
    const int q = lane >> 4, l15 = lane & 15;
    for (int p = 0; p < 8; ++p) {
        int j = p * 16 + (tid >> 4), o0 = (tid & 15) * 8;
        h8_t v = *(const h8_t*)&SRC[((size_t)b * NC + j) * DD + ob * 128 + o0];
        for (int i = 0; i < 8; ++i) T[(o0 + i) * 136 + j] = v[i];
    }
    __syncthreads();
    f32x4 acc[2][8];
    for (int mt = 0; mt < 2; ++mt)
        for (int ot = 0; ot < 8; ++ot) acc[mt][ot] = (f32x4){0.f, 0.f, 0.f, 0.f};
    for (int kd = 0; kd < 4; ++kd) {
        h8_t af[2];
        for (int mt = 0; mt < 2; ++mt) {
            int n = w * 32 + mt * 16 + l15;
            af[mt] = *(const h8_t*)&GT[((size_t)b * NC + n) * NC + kd * 32 + q * 8];
        }
        h8_t bf[8];
        for (int ot = 0; ot < 8; ++ot)
            bf[ot] = *(const h8_t*)&T[(ot * 16 + l15) * 136 + kd * 32 + q * 8];
        for (int mt = 0; mt < 2; ++mt)
            for (int ot = 0; ot < 8; ++ot)
                acc[mt][ot] = MFMA(af[mt], bf[ot], acc[mt][ot], 0, 0, 0);
    }
    for (int mt = 0; mt < 2; ++mt)
        for (int ot = 0; ot < 8; ++ot)
            for (int r = 0; r < 4; ++r) {
                int n = w * 32 + mt * 16 + q * 4 + r;
                int o = ob * 128 + ot * 16 + l15;
                size_t ix = ((size_t)b * NC + n) * DD + o;
                DST[ix] = (_Float16)((float)V0T[ix] + acc[mt][ot][r]);
            }
}

// ------------------------------------------------- Kwhat: What = K@M0^T + HT@Vhat
// epilogue reduces sv[n] = sum_o What*Vhat, svv[n] = sum_o Vhat^2 (partials per ob)
__global__ __launch_bounds__(256) void k_what(
    const _Float16* __restrict__ KF, const _Float16* __restrict__ M0H,
    const _Float16* __restrict__ HT, const _Float16* __restrict__ VHT,
    float* __restrict__ SVP, float* __restrict__ SVVP)
{
    __shared__ _Float16 T[128 * 136];
    const int b = blockIdx.x / 3, ob = blockIdx.x % 3;
    const int tid = threadIdx.x, lane = tid & 63, w = tid >> 6;
    const int q = lane >> 4, l15 = lane & 15;
    for (int p = 0; p < 8; ++p) {
        int j = p * 16 + (tid >> 4), o0 = (tid & 15) * 8;
        h8_t v = *(const h8_t*)&VHT[((size_t)b * NC + j) * DD + ob * 128 + o0];
        for (int i = 0; i < 8; ++i) T[(o0 + i) * 136 + j] = v[i];
    }
    __syncthreads();
    f32x4 acc[2][8];
    for (int mt = 0; mt < 2; ++mt)
        for (int ot = 0; ot < 8; ++ot) acc[mt][ot] = (f32x4){0.f, 0.f, 0.f, 0.f};
    for (int kd = 0; kd < 12; ++kd) {   // K @ M0^T
        h8_t af[2];
        for (int mt = 0; mt < 2; ++mt) {
            int n = w * 32 + mt * 16 + l15;
            af[mt] = *(const h8_t*)&KF[((size_t)b * NC + n) * DD + kd * 32 + q * 8];
        }
        h8_t bf[8];
        for (int ot = 0; ot < 8; ++ot) {
            int o = ob * 128 + ot * 16 + l15;
            bf[ot] = *(const h8_t*)&M0H[(size_t)o * DD + kd * 32 + q * 8];
        }
        for (int mt = 0; mt < 2; ++mt)
            for (int ot = 0; ot < 8; ++ot)
                acc[mt][ot] = MFMA(af[mt], bf[ot], acc[mt][ot], 0, 0, 0);
    }
    for (int kd = 0; kd < 4; ++kd) {    // + HT @ Vhat
        h8_t af[2];
        for (int mt = 0; mt < 2; ++mt) {
            int n = w * 32 + mt * 16 + l15;
            af[mt] = *(const h8_t*)&HT[((size_t)b * NC + n) * NC + kd * 32 + q * 8];
        }
        h8_t bf[8];
        for (int ot = 0; ot < 8; ++ot)
            bf[ot] = *(const h8_t*)&T[(ot * 16 + l15) * 136 + kd * 32 + q * 8];
        for (int mt = 0; mt < 2; ++mt)
            for (int ot = 0; ot < 8; ++ot)
                acc[mt][ot] = MFMA(af[mt], bf[ot], acc[mt][ot], 0, 0, 0);
    }
    for (int mt = 0; mt < 2; ++mt)
        for (int r = 0; r < 4; ++r) {
            int n = w * 32 + mt * 16 + q * 4 + r;
            float sv = 0.f, svv = 0.f;
            for (int ot = 0; ot < 8; ++ot) {
                float vh = (float)T[(ot * 16 + l15) * 136 + n];
                sv += acc[mt][ot][r] * vh;
                svv += vh * vh;
            }
            sv += __shfl_xor(sv, 1); svv += __shfl_xor(svv, 1);
            sv += __shfl_xor(sv, 2); svv += __shfl_xor(svv, 2);
            sv += __shfl_xor(sv, 4); svv += __shfl_xor(svv, 4);
            sv += __shfl_xor(sv, 8); svv += __shfl_xor(svv, 8);
            if (l15 == 0) {
                SVP[(b * 3 + ob) * NC + n] = sv;
                SVVP[(b * 3 + ob) * NC + n] = svv;
            }
        }
}

// ------------------------------------------------- Kscalar: phi/rho scan
__global__ __launch_bounds__(256) void k_scalar(
    const float* __restrict__ M0, const float* __restrict__ AB,
    const float* __restrict__ SKK, const float* __restrict__ SVP,
    const float* __restrict__ SVVP, float* __restrict__ SIG,
    float* __restrict__ FRHO)
{
    const int b = blockIdx.x, tid = threadIdx.x;
    __shared__ float red[4];
    __shared__ float sig_s[NC];
    float p = 0.f;
    const float4* m4 = (const float4*)M0;
    for (int i = tid; i < DD * DD / 4; i += 256) {
        float4 v = m4[i];
        p += v.x * v.x + v.y * v.y + v.z * v.z + v.w * v.w;
    }
    for (int off = 32; off; off >>= 1) p += __shfl_xor(p, off);
    if ((tid & 63) == 0) red[tid >> 6] = p;
    __syncthreads();
    if (tid == 0) {
        float phi2 = red[0] + red[1] + red[2] + red[3];
        float an = 1.f, rho = 1.f;
        for (int n = 0; n < NC; ++n) {
            float A = AB[(b * NC + n) * 2], Bc = AB[(b * NC + n) * 2 + 1];
            sig_s[n] = rho * an;
            float a2 = an * an;
            float sv = a2 * (SVP[(b * 3 + 0) * NC + n] + SVP[(b * 3 + 1) * NC + n]
                             + SVP[(b * 3 + 2) * NC + n]);
            float svv = a2 * (SVVP[(b * 3 + 0) * NC + n] + SVVP[(b * 3 + 1) * NC + n]
                              + SVVP[(b * 3 + 2) * NC + n]);
            phi2 = A * A * phi2 + 2.f * A * Bc * sv + Bc * Bc * svv * SKK[b * NC + n];
            float s = fminf(30.f / (rho * sqrtf(phi2) + 1e-6f), 1.f);
            rho *= s; an *= A;
        }
        FRHO[b] = rho * an;
    }
    __syncthreads();
    for (int i = tid; i < NC; i += 256) SIG[b * NC + i] = sig_s[i];
}

// ------------------------------------------------- Ktrans: WTH/KFT transposes
// WTH[o][j] = tau_j * Vhat[j][o] (f16);  KFT[d][j] = KF[j][d]
__global__ __launch_bounds__(256) void k_trans(
    const _Float16* __restrict__ VHT, const _Float16* __restrict__ KF,
    const float* __restrict__ TAB, _Float16* __restrict__ WTH,
    _Float16* __restrict__ KFT)
{
    __shared__ _Float16 T[128 * 72];
    const int b = blockIdx.x / 6, ob = blockIdx.x % 6, tid = threadIdx.x;
    for (int pass = 0; pass < 2; ++pass) {
        const _Float16* Src = pass ? KF : VHT;
        _Float16* Dst = pass ? KFT : WTH;
        if (pass) __syncthreads();
        for (int pp = 0; pp < 4; ++pp) {
            int j = pp * 32 + (tid >> 3), oo = (tid & 7) * 8;
            *(h8_t*)&T[j * 72 + oo] =
                *(const h8_t*)&Src[((size_t)b * NC + j) * DD + ob * 64 + oo];
        }
        __syncthreads();
        for (int c = 0; c < 4; ++c) {
            int idx = c * 256 + tid;
            int ol = idx >> 4, jc = (idx & 15) * 8;
            h8_t v;
            for (int i = 0; i < 8; ++i) {
                float t = (float)T[(jc + i) * 72 + ol];
                if (!pass) t *= TAB[b * NC + jc + i];
                v[i] = (_Float16)t;
            }
            *(h8_t*)&Dst[((size_t)b * DD + ob * 64 + ol) * NC + jc] = v;
        }
    }
}

// ------------------------------------------------------------ K4: output GEMM
// per (b,n) WG: out_n = sig_n * [chunk_n @ M0^T + (chunk_n @ K_{<n}) @ WTH^T]
// tail WGs: M_fin = FRHO * (M0 + WTH @ KFT^T)
__global__ __launch_bounds__(256) void k4_out(
    const _Float16* __restrict__ XF, const _Float16* __restrict__ M0H,
    const _Float16* __restrict__ KF, const _Float16* __restrict__ WTH,
    const _Float16* __restrict__ KFT, const float* __restrict__ SIG,
    const float* __restrict__ FRHO, const float* __restrict__ M0,
    float* __restrict__ out)
{
    const int tid = threadIdx.x, lane = tid & 63, w = tid >> 6;
    const int q = lane >> 4, l15 = lane & 15;

    if (blockIdx.x >= BB * NC) {  // M_fin tail: 96 WGs
        const int tw = blockIdx.x - BB * NC;
        const int b = tw / 12, sub = tw % 12;
        const int obk = sub >> 1, dh = sub & 1;
        const int o_t = obk * 64 + w * 16;
        f32x4 acc[12];
        for (int dt = 0; dt < 12; ++dt) acc[dt] = (f32x4){0.f, 0.f, 0.f, 0.f};
        for (int kd = 0; kd < 4; ++kd) {
            h8_t af = *(const h8_t*)&WTH[((size_t)b * DD + o_t + l15) * NC + kd * 32 + q * 8];
            for (int dt = 0; dt < 12; ++dt) {
                int d = dh * 192 + dt * 16 + l15;
                h8_t bf = *(const h8_t*)&KFT[((size_t)b * DD + d) * NC + kd * 32 + q * 8];
                acc[dt] = MFMA(af, bf, acc[dt], 0, 0, 0);
            }
        }
        float fr = FRHO[b];
        float* dst = out + (size_t)BB * SS * DD;
        for (int dt = 0; dt < 12; ++dt)
            for (int r = 0; r < 4; ++r) {
                int o = o_t + q * 4 + r, d = dh * 192 + dt * 16 + l15;
                dst[((size_t)b * DD + o) * DD + d] =
                    fr * (M0[(size_t)o * DD + d] + acc[dt][r]);
            }
        return;
    }

    const int b = blockIdx.x >> 7, n = blockIdx.x & 127;
    __shared__ _Float16 lds[CH * 392];

    const size_t chunk_off = (size_t)(b * SS + n * CH) * DD;
    {
        const h4_t* __restrict__ xs = (const h4_t*)(XF + chunk_off);
        for (int i = tid; i < CH * DD / 4; i += 256) {
            int base = i * 4, r = base / DD, c = base % DD;
            *(h4_t*)&lds[r * 392 + c] = xs[i];
        }
    }
    __syncthreads();

    f32x4 acc[4][6];
    for (int mi = 0; mi < 4; ++mi)
        for (int nj = 0; nj < 6; ++nj) acc[mi][nj] = (f32x4){0.f, 0.f, 0.f, 0.f};

    for (int kd = 0; kd < 12; ++kd) {  // chunk @ M0^T
        h8_t af[4];
        for (int mi = 0; mi < 4; ++mi)
            af[mi] = *(const h8_t*)&lds[(mi * 16 + l15) * 392 + kd * 32 + q * 8];
        h8_t bf[6];
        for (int nj = 0; nj < 6; ++nj) {
            int o = w * 96 + nj * 16 + l15;
            bf[nj] = *(const h8_t*)&M0H[(size_t)o * DD + kd * 32 + q * 8];
        }
        for (int mi = 0; mi < 4; ++mi)
            for (int nj = 0; nj < 6; ++nj)
                acc[mi][nj] = MFMA(af[mi], bf[nj], acc[mi][nj], 0, 0, 0);
    }

    const int nb = (n + 31) >> 5;
    const bool sact = (w * 32 < n);
    f32x4 sacc[4][2];
    if (sact) {
        for (int mi = 0; mi < 4; ++mi)
            for (int nj = 0; nj < 2; ++nj) sacc[mi][nj] = (f32x4){0.f, 0.f, 0.f, 0.f};
        for (int kd = 0; kd < 12; ++kd) {
            h8_t af[4];
            for (int mi = 0; mi < 4; ++mi)
                af[mi] = *(const h8_t*)&lds[(mi * 16 + l15) * 392 + kd * 32 + q * 8];
            h8_t bf[2];
            for (int nj = 0; nj < 2; ++nj) {
                int j = w * 32 + nj * 16 + l15;
                bf[nj] = *(const h8_t*)&KF[((size_t)(b * NC) + j) * DD + kd * 32 + q * 8];
            }
            for (int mi = 0; mi < 4; ++mi)
                for (int nj = 0; nj < 2; ++nj)
                    sacc[mi][nj] = MFMA(af[mi], bf[nj], sacc[mi][nj], 0, 0, 0);
        }
    }
    __syncthreads();
    if (sact) {
        for (int mi = 0; mi < 4; ++mi)
            for (int nj = 0; nj < 2; ++nj)
                for (int r = 0; r < 4; ++r) {
                    int c = mi * 16 + q * 4 + r, j = w * 32 + nj * 16 + l15;
                    lds[c * 136 + j] = (_Float16)((j < n) ? sacc[mi][nj][r] : 0.f);
                }
    }
    __syncthreads();

    for (int kb = 0; kb < nb; ++kb) {  // S @ WTH^T
        h8_t af[4];
        for (int mi = 0; mi < 4; ++mi)
            af[mi] = *(const h8_t*)&lds[(mi * 16 + l15) * 136 + kb * 32 + q * 8];
        h8_t bf[6];
        for (int nj = 0; nj < 6; ++nj) {
            int o = w * 96 + nj * 16 + l15;
            bf[nj] = *(const h8_t*)&WTH[((size_t)(b * DD) + o) * NC + kb * 32 + q * 8];
        }
        for (int mi = 0; mi < 4; ++mi)
            for (int nj = 0; nj < 6; ++nj)
                acc[mi][nj] = MFMA(af[mi], bf[nj], acc[mi][nj], 0, 0, 0);
    }

    const float sg = SIG[b * NC + n];
    for (int mi = 0; mi < 4; ++mi)
        for (int nj = 0; nj < 6; ++nj)
            for (int r = 0; r < 4; ++r) {
                int c = mi * 16 + q * 4 + r, o = w * 96 + nj * 16 + l15;
                out[chunk_off + (size_t)c * DD + o] = sg * acc[mi][nj][r];
            }
}

// ---------------------------------------------------------------- launch
extern "C" void kernel_launch(void* const* d_in, const int* in_sizes, int n_in,
                              void* d_out, int out_size, void* d_ws, size_t ws_size,
                              hipStream_t stream) {
    (void)in_sizes; (void)n_in; (void)out_size; (void)ws_size;
    const float* x         = (const float*)d_in[0];
    const float* M0        = (const float*)d_in[1];
    const float* eta_raw   = (const float*)d_in[2];
    const float* alpha_raw = (const float*)d_in[3];
    const float* gate_w    = (const float*)d_in[4];
    const float* gate_b    = (const float*)d_in[5];
    float* out = (float*)d_out;
    char* ws = (char*)d_ws;

    _Float16* XF  = (_Float16*)(ws);                 // 50,331,648
    _Float16* UF  = (_Float16*)(ws + 50331648);      //    786,432
    _Float16* KF  = (_Float16*)(ws + 51118080);      //    786,432
    _Float16* M0H = (_Float16*)(ws + 51904512);      //    294,912
    _Float16* GT  = (_Float16*)(ws + 52199424);      //    262,144
    _Float16* HT  = (_Float16*)(ws + 52461568);      //    262,144
    _Float16* V0T = (_Float16*)(ws + 52723712);      //    786,432
    _Float16* VTA = (_Float16*)(ws + 53510144);      //    786,432
    _Float16* VTB = (_Float16*)(ws + 54296576);      //    786,432
    _Float16* WTH = (_Float16*)(ws + 55083008);      //    786,432
    _Float16* KFT = (_Float16*)(ws + 55869440);      //    786,432
    float*    AB  = (float*)(ws + 56655872);         //      8,192
    float*    TAB = (float*)(ws + 56664064);         //      4,096
    float*    SKK = (float*)(ws + 56668160);         //      4,096
    float*    SVP = (float*)(ws + 56672256);         //     12,288
    float*    SVVP= (float*)(ws + 56684544);         //     12,288
    float*    SIG = (float*)(ws + 56696832);         //      4,096
    float*    FRHO= (float*)(ws + 56700928);         //        256

    k1_stats<<<dim3(BB * NC), dim3(512), 0, stream>>>(
        x, M0, eta_raw, alpha_raw, gate_w, gate_b, XF, UF, KF, AB, TAB, SKK, M0H);
    k_gram<<<dim3(BB), dim3(256), 0, stream>>>(KF, UF, TAB, GT, HT);
    k_v0<<<dim3(BB * 3), dim3(256), 0, stream>>>(UF, M0H, V0T);
    k_chain<<<dim3(BB * 3), dim3(256), 0, stream>>>(V0T, V0T, GT, VTA);
    k_chain<<<dim3(BB * 3), dim3(256), 0, stream>>>(VTA, V0T, GT, VTB);
    k_what<<<dim3(BB * 3), dim3(256), 0, stream>>>(KF, M0H, HT, VTB, SVP, SVVP);
    k_scalar<<<dim3(BB), dim3(256), 0, stream>>>(M0, AB, SKK, SVP, SVVP, SIG, FRHO);
    k_trans<<<dim3(BB * 6), dim3(256), 0, stream>>>(VTB, KF, TAB, WTH, KFT);
    k4_out<<<dim3(BB * NC + 96), dim3(256), 0, stream>>>(
        XF, M0H, KF, WTH, KFT, SIG, FRHO, M0, out);
}

// Round 3
// 489.608 us; speedup vs baseline: 1.2366x; 1.0056x over previous
//
#include <hip/hip_runtime.h>
#include <cmath>

#define BB 8
#define SS 8192
#define DD 384
#define CH 64
#define NC 128

typedef _Float16 h8_t __attribute__((ext_vector_type(8)));
typedef _Float16 h4_t __attribute__((ext_vector_type(4)));
typedef float f32x4 __attribute__((ext_vector_type(4)));

#define MFMA __builtin_amdgcn_mfma_f32_16x16x32_f16

// ---------------------------------------------------------------- K1: stats
// per (b,n): row norms, kmean, u = xbar-kmean, gate -> A,B, tau=B/A, skk=|k|^2
// x -> f16 (XF), M0 -> f16 (first 64 WGs). f16 LDS tile (50 KB) -> 3 WGs/CU.
__global__ __launch_bounds__(512) void k1_stats(
    const float* __restrict__ x, const float* __restrict__ M0,
    const float* __restrict__ eta_raw, const float* __restrict__ alpha_raw,
    const float* __restrict__ gate_w, const float* __restrict__ gate_b,
    _Float16* __restrict__ XF, _Float16* __restrict__ UF,
    _Float16* __restrict__ KF, float* __restrict__ AB, float* __restrict__ TAB,
    float* __restrict__ SKK, _Float16* __restrict__ M0H)
{
    __shared__ _Float16 ch[CH * 392];   // 50176 B
    __shared__ float rinv[CH];
    __shared__ float redg[8], redk[8];
    const int wg = blockIdx.x, tid = threadIdx.x;
    const int b = wg >> 7, n = wg & 127;
    const int lane = tid & 63, wid = tid >> 6;

    if (wg < 64) {  // cast M0 -> f16
        for (int i = tid; i < 2304; i += 512) {
            int idx = wg * 2304 + i;
            M0H[idx] = (_Float16)M0[idx];
        }
    }

    const size_t chunk_off = (size_t)(b * SS + n * CH) * DD;
    const float4* __restrict__ xin = (const float4*)(x + chunk_off);
    h4_t* __restrict__ xf = (h4_t*)(XF + chunk_off);
    for (int i = tid; i < CH * DD / 4; i += 512) {
        float4 v = xin[i];
        int base = i * 4, r = base / DD, c = base % DD;
        h4_t h; h[0] = (_Float16)v.x; h[1] = (_Float16)v.y;
        h[2] = (_Float16)v.z; h[3] = (_Float16)v.w;
        *(h4_t*)&ch[r * 392 + c] = h;
        xf[i] = h;
    }
    __syncthreads();

    for (int r = wid * 8; r < wid * 8 + 8; ++r) {
        float s = 0.f;
        for (int t = 0; t < 6; ++t) {
            float v = (float)ch[r * 392 + lane + 64 * t]; s += v * v;
        }
        for (int off = 32; off; off >>= 1) s += __shfl_xor(s, off);
        if (lane == 0) rinv[r] = 1.f / fmaxf(sqrtf(s), 1e-5f);
    }
    __syncthreads();

    float gpart = 0.f, skkp = 0.f;
    for (int d = tid; d < DD; d += 512) {
        float xa = 0.f, km = 0.f;
        for (int c = 0; c < CH; ++c) {
            float v = (float)ch[c * 392 + d]; xa += v; km += v * rinv[c];
        }
        xa *= (1.f / 64.f); km *= (1.f / 64.f);
        int o = (b * NC + n) * DD + d;
        UF[o] = (_Float16)(xa - km);
        KF[o] = (_Float16)km;
        gpart += km * gate_w[d];
        skkp += km * km;
    }
    for (int off = 32; off; off >>= 1) {
        gpart += __shfl_xor(gpart, off);
        skkp += __shfl_xor(skkp, off);
    }
    if (lane == 0) { redg[wid] = gpart; redk[wid] = skkp; }
    __syncthreads();
    if (tid == 0) {
        float gsum = 0.f, ks = 0.f;
        for (int i = 0; i < 8; ++i) { gsum += redg[i]; ks += redk[i]; }
        float g = 1.f / (1.f + expf(-(gsum + gate_b[0])));
        float eta = 0.2f / (1.f + expf(-eta_raw[0]));
        float alpha = 0.5f + 0.5f / (1.f + expf(-alpha_raw[0]));
        float A = g * alpha + 1.f - g;
        float Bc = g * eta;
        AB[wg * 2 + 0] = A;
        AB[wg * 2 + 1] = Bc;
        TAB[wg] = Bc / A;
        SKK[wg] = ks;
    }
}

// ---------------------------------------------------------------- kS: scores
// S[b][n][c][j] = (j<n) ? x_c . k_j : 0, f16. Wave w covers j in [32w,32w+32);
// inactive waves (32w >= n) skip entirely (k4 only reads j < 32*ceil(n/32)).
__global__ __launch_bounds__(256) void k_score(
    const _Float16* __restrict__ XF, const _Float16* __restrict__ KF,
    _Float16* __restrict__ SG)
{
    const int b = blockIdx.x >> 7, n = blockIdx.x & 127;
    const int tid = threadIdx.x, lane = tid & 63, w = tid >> 6;
    const int q = lane >> 4, l15 = lane & 15;
    if (w * 32 >= n) return;
    const size_t chunk_off = (size_t)(b * SS + n * CH) * DD;
    f32x4 acc[4][2];
    for (int mi = 0; mi < 4; ++mi)
        for (int nj = 0; nj < 2; ++nj) acc[mi][nj] = (f32x4){0.f, 0.f, 0.f, 0.f};
    for (int kd = 0; kd < 12; ++kd) {
        h8_t af[4];
        for (int mi = 0; mi < 4; ++mi)
            af[mi] = *(const h8_t*)&XF[chunk_off + (size_t)(mi * 16 + l15) * DD + kd * 32 + q * 8];
        h8_t bf[2];
        for (int nj = 0; nj < 2; ++nj) {
            int j = w * 32 + nj * 16 + l15;
            bf[nj] = *(const h8_t*)&KF[((size_t)b * NC + j) * DD + kd * 32 + q * 8];
        }
        for (int mi = 0; mi < 4; ++mi)
            for (int nj = 0; nj < 2; ++nj)
                acc[mi][nj] = MFMA(af[mi], bf[nj], acc[mi][nj], 0, 0, 0);
    }
    _Float16* Sout = SG + ((size_t)(b * NC + n)) * CH * NC;
    for (int mi = 0; mi < 4; ++mi)
        for (int nj = 0; nj < 2; ++nj)
            for (int r = 0; r < 4; ++r) {
                int c = mi * 16 + q * 4 + r, j = w * 32 + nj * 16 + l15;
                Sout[c * NC + j] = (_Float16)((j < n) ? acc[mi][nj][r] : 0.f);
            }
}

// ---------------------------------------------------------------- kA: gram + v0
// WGs 0..7: GT/HT gram per batch. WGs 8..31: V0T = U @ M0^T.
__global__ __launch_bounds__(256) void kA(
    const _Float16* __restrict__ KF, const _Float16* __restrict__ UF,
    const _Float16* __restrict__ M0H, const float* __restrict__ TAB,
    _Float16* __restrict__ GT, _Float16* __restrict__ HT,
    _Float16* __restrict__ V0T)
{
    const int tid = threadIdx.x, lane = tid & 63, w = tid >> 6;
    const int q = lane >> 4, l15 = lane & 15;
    if (blockIdx.x < 8) {
        const int b = blockIdx.x;
        const _Float16* Kb = KF + (size_t)b * NC * DD;
        const _Float16* Ub = UF + (size_t)b * NC * DD;
        for (int pass = 0; pass < 2; ++pass) {
            const _Float16* Bm = pass ? Kb : Ub;
            _Float16* Out = pass ? HT : GT;
            f32x4 acc[2][8];
            for (int mt = 0; mt < 2; ++mt)
                for (int nt = 0; nt < 8; ++nt) acc[mt][nt] = (f32x4){0.f, 0.f, 0.f, 0.f};
            for (int kd = 0; kd < 12; ++kd) {
                h8_t af[2];
                for (int mt = 0; mt < 2; ++mt) {
                    int j = w * 32 + mt * 16 + l15;
                    af[mt] = *(const h8_t*)&Kb[(size_t)j * DD + kd * 32 + q * 8];
                }
                h8_t bf[8];
                for (int nt = 0; nt < 8; ++nt) {
                    int nn = nt * 16 + l15;
                    bf[nt] = *(const h8_t*)&Bm[(size_t)nn * DD + kd * 32 + q * 8];
                }
                for (int mt = 0; mt < 2; ++mt)
                    for (int nt = 0; nt < 8; ++nt)
                        acc[mt][nt] = MFMA(af[mt], bf[nt], acc[mt][nt], 0, 0, 0);
            }
            for (int mt = 0; mt < 2; ++mt)
                for (int nt = 0; nt < 8; ++nt)
                    for (int r = 0; r < 4; ++r) {
                        int j = w * 32 + mt * 16 + q * 4 + r;
                        int nn = nt * 16 + l15;
                        float v = (j < nn) ? TAB[b * NC + j] * acc[mt][nt][r] : 0.f;
                        Out[((size_t)b * NC + nn) * NC + j] = (_Float16)v;
                    }
        }
    } else {
        const int idx = blockIdx.x - 8;
        const int b = idx / 3, ob = idx % 3;
        f32x4 acc[2][8];
        for (int mt = 0; mt < 2; ++mt)
            for (int ot = 0; ot < 8; ++ot) acc[mt][ot] = (f32x4){0.f, 0.f, 0.f, 0.f};
        for (int kd = 0; kd < 12; ++kd) {
            h8_t af[2];
            for (int mt = 0; mt < 2; ++mt) {
                int n = w * 32 + mt * 16 + l15;
                af[mt] = *(const h8_t*)&UF[((size_t)b * NC + n) * DD + kd * 32 + q * 8];
            }
            h8_t bf[8];
            for (int ot = 0; ot < 8; ++ot) {
                int o = ob * 128 + ot * 16 + l15;
                bf[ot] = *(const h8_t*)&M0H[(size_t)o * DD + kd * 32 + q * 8];
            }
            for (int mt = 0; mt < 2; ++mt)
                for (int ot = 0; ot < 8; ++ot)
                    acc[mt][ot] = MFMA(af[mt], bf[ot], acc[mt][ot], 0, 0, 0);
        }
        for (int mt = 0; mt < 2; ++mt)
            for (int ot = 0; ot < 8; ++ot)
                for (int r = 0; r < 4; ++r) {
                    int n = w * 32 + mt * 16 + q * 4 + r;
                    int o = ob * 128 + ot * 16 + l15;
                    V0T[((size_t)b * NC + n) * DD + o] = (_Float16)acc[mt][ot][r];
                }
    }
}

// ------------------------------------------------------- Kchain: DST = V0T + GT @ SRC
__global__ __launch_bounds__(256) void k_chain(
    const _Float16* __restrict__ SRC, const _Float16* __restrict__ V0T,
    const _Float16* __restrict__ GT, _Float16* __restrict__ DST)
{
    __shared__ _Float16 T[128 * 136];
    const int b = blockIdx.x / 3, ob = blockIdx.x % 3;
    const int tid = threadIdx.x, lane = tid & 63, w = tid >> 6;
    const int q = lane >> 4, l15 = lane & 15;
    for (int p = 0; p < 8; ++p) {
        int j = p * 16 + (tid >> 4), o0 = (tid & 15) * 8;
        h8_t v = *(const h8_t*)&SRC[((size_t)b * NC + j) * DD + ob * 128 + o0];
        for (int i = 0; i < 8; ++i) T[(o0 + i) * 136 + j] = v[i];
    }
    __syncthreads();
    f32x4 acc[2][8];
    for (int mt = 0; mt < 2; ++mt)
        for (int ot = 0; ot < 8; ++ot) acc[mt][ot] = (f32x4){0.f, 0.f, 0.f, 0.f};
    for (int kd = 0; kd < 4; ++kd) {
        h8_t af[2];
        for (int mt = 0; mt < 2; ++mt) {
            int n = w * 32 + mt * 16 + l15;
            af[mt] = *(const h8_t*)&GT[((size_t)b * NC + n) * NC + kd * 32 + q * 8];
        }
        h8_t bf[8];
        for (int ot = 0; ot < 8; ++ot)
            bf[ot] = *(const h8_t*)&T[(ot * 16 + l15) * 136 + kd * 32 + q * 8];
        for (int mt = 0; mt < 2; ++mt)
            for (int ot = 0; ot < 8; ++ot)
                acc[mt][ot] = MFMA(af[mt], bf[ot], acc[mt][ot], 0, 0, 0);
    }
    for (int mt = 0; mt < 2; ++mt)
        for (int ot = 0; ot < 8; ++ot)
            for (int r = 0; r < 4; ++r) {
                int n = w * 32 + mt * 16 + q * 4 + r;
                int o = ob * 128 + ot * 16 + l15;
                size_t ix = ((size_t)b * NC + n) * DD + o;
                DST[ix] = (_Float16)((float)V0T[ix] + acc[mt][ot][r]);
            }
}

// ------------------------------------------------- Kwhat: What = K@M0^T + HT@Vhat
__global__ __launch_bounds__(256) void k_what(
    const _Float16* __restrict__ KF, const _Float16* __restrict__ M0H,
    const _Float16* __restrict__ HT, const _Float16* __restrict__ VHT,
    float* __restrict__ SVP, float* __restrict__ SVVP)
{
    __shared__ _Float16 T[128 * 136];
    const int b = blockIdx.x / 3, ob = blockIdx.x % 3;
    const int tid = threadIdx.x, lane = tid & 63, w = tid >> 6;
    const int q = lane >> 4, l15 = lane & 15;
    for (int p = 0; p < 8; ++p) {
        int j = p * 16 + (tid >> 4), o0 = (tid & 15) * 8;
        h8_t v = *(const h8_t*)&VHT[((size_t)b * NC + j) * DD + ob * 128 + o0];
        for (int i = 0; i < 8; ++i) T[(o0 + i) * 136 + j] = v[i];
    }
    __syncthreads();
    f32x4 acc[2][8];
    for (int mt = 0; mt < 2; ++mt)
        for (int ot = 0; ot < 8; ++ot) acc[mt][ot] = (f32x4){0.f, 0.f, 0.f, 0.f};
    for (int kd = 0; kd < 12; ++kd) {
        h8_t af[2];
        for (int mt = 0; mt < 2; ++mt) {
            int n = w * 32 + mt * 16 + l15;
            af[mt] = *(const h8_t*)&KF[((size_t)b * NC + n) * DD + kd * 32 + q * 8];
        }
        h8_t bf[8];
        for (int ot = 0; ot < 8; ++ot) {
            int o = ob * 128 + ot * 16 + l15;
            bf[ot] = *(const h8_t*)&M0H[(size_t)o * DD + kd * 32 + q * 8];
        }
        for (int mt = 0; mt < 2; ++mt)
            for (int ot = 0; ot < 8; ++ot)
                acc[mt][ot] = MFMA(af[mt], bf[ot], acc[mt][ot], 0, 0, 0);
    }
    for (int kd = 0; kd < 4; ++kd) {
        h8_t af[2];
        for (int mt = 0; mt < 2; ++mt) {
            int n = w * 32 + mt * 16 + l15;
            af[mt] = *(const h8_t*)&HT[((size_t)b * NC + n) * NC + kd * 32 + q * 8];
        }
        h8_t bf[8];
        for (int ot = 0; ot < 8; ++ot)
            bf[ot] = *(const h8_t*)&T[(ot * 16 + l15) * 136 + kd * 32 + q * 8];
        for (int mt = 0; mt < 2; ++mt)
            for (int ot = 0; ot < 8; ++ot)
                acc[mt][ot] = MFMA(af[mt], bf[ot], acc[mt][ot], 0, 0, 0);
    }
    for (int mt = 0; mt < 2; ++mt)
        for (int r = 0; r < 4; ++r) {
            int n = w * 32 + mt * 16 + q * 4 + r;
            float sv = 0.f, svv = 0.f;
            for (int ot = 0; ot < 8; ++ot) {
                float vh = (float)T[(ot * 16 + l15) * 136 + n];
                sv += acc[mt][ot][r] * vh;
                svv += vh * vh;
            }
            sv += __shfl_xor(sv, 1); svv += __shfl_xor(svv, 1);
            sv += __shfl_xor(sv, 2); svv += __shfl_xor(svv, 2);
            sv += __shfl_xor(sv, 4); svv += __shfl_xor(svv, 4);
            sv += __shfl_xor(sv, 8); svv += __shfl_xor(svv, 8);
            if (l15 == 0) {
                SVP[(b * 3 + ob) * NC + n] = sv;
                SVVP[(b * 3 + ob) * NC + n] = svv;
            }
        }
}

// ---------------------------------------------- kC: trans (WGs 0..47) + scalar scan (48..55)
__global__ __launch_bounds__(256) void kC(
    const _Float16* __restrict__ VHT, const _Float16* __restrict__ KF,
    const float* __restrict__ TAB, const float* __restrict__ M0,
    const float* __restrict__ AB, const float* __restrict__ SKK,
    const float* __restrict__ SVP, const float* __restrict__ SVVP,
    _Float16* __restrict__ WTH, _Float16* __restrict__ KFT,
    float* __restrict__ SIG, float* __restrict__ FRHO)
{
    const int tid = threadIdx.x;
    if (blockIdx.x < 48) {
        __shared__ _Float16 T[128 * 72];
        const int b = blockIdx.x / 6, ob = blockIdx.x % 6;
        for (int pass = 0; pass < 2; ++pass) {
            const _Float16* Src = pass ? KF : VHT;
            _Float16* Dst = pass ? KFT : WTH;
            if (pass) __syncthreads();
            for (int pp = 0; pp < 4; ++pp) {
                int j = pp * 32 + (tid >> 3), oo = (tid & 7) * 8;
                *(h8_t*)&T[j * 72 + oo] =
                    *(const h8_t*)&Src[((size_t)b * NC + j) * DD + ob * 64 + oo];
            }
            __syncthreads();
            for (int c = 0; c < 4; ++c) {
                int idx = c * 256 + tid;
                int ol = idx >> 4, jc = (idx & 15) * 8;
                h8_t v;
                for (int i = 0; i < 8; ++i) {
                    float t = (float)T[(jc + i) * 72 + ol];
                    if (!pass) t *= TAB[b * NC + jc + i];
                    v[i] = (_Float16)t;
                }
                *(h8_t*)&Dst[((size_t)b * DD + ob * 64 + ol) * NC + jc] = v;
            }
        }
    } else {
        __shared__ float sA[NC], sB[NC], sSV[NC], sVV[NC], sKK[NC], sig_s[NC];
        __shared__ float red[4];
        const int b = blockIdx.x - 48;
        for (int i = tid; i < NC; i += 256) {
            sA[i] = AB[(b * NC + i) * 2];
            sB[i] = AB[(b * NC + i) * 2 + 1];
            sSV[i] = SVP[(b * 3 + 0) * NC + i] + SVP[(b * 3 + 1) * NC + i]
                     + SVP[(b * 3 + 2) * NC + i];
            sVV[i] = SVVP[(b * 3 + 0) * NC + i] + SVVP[(b * 3 + 1) * NC + i]
                     + SVVP[(b * 3 + 2) * NC + i];
            sKK[i] = SKK[b * NC + i];
        }
        float p = 0.f;
        const float4* m4 = (const float4*)M0;
        for (int i = tid; i < DD * DD / 4; i += 256) {
            float4 v = m4[i];
            p += v.x * v.x + v.y * v.y + v.z * v.z + v.w * v.w;
        }
        for (int off = 32; off; off >>= 1) p += __shfl_xor(p, off);
        if ((tid & 63) == 0) red[tid >> 6] = p;
        __syncthreads();
        if (tid == 0) {
            float phi2 = red[0] + red[1] + red[2] + red[3];
            float an = 1.f, rho = 1.f;
            for (int n = 0; n < NC; ++n) {
                float A = sA[n], Bc = sB[n];
                sig_s[n] = rho * an;
                float a2 = an * an;
                phi2 = A * A * phi2 + 2.f * A * Bc * a2 * sSV[n]
                       + Bc * Bc * a2 * sVV[n] * sKK[n];
                float s = fminf(30.f / (rho * sqrtf(phi2) + 1e-6f), 1.f);
                rho *= s; an *= A;
            }
            FRHO[b] = rho * an;
        }
        __syncthreads();
        for (int i = tid; i < NC; i += 256) SIG[b * NC + i] = sig_s[i];
    }
}

// ------------------------------------------------------------ K4: output GEMM
// per (b,n): out_n = sig_n * [chunk @ M0^T + S_n @ WTH^T].  No LDS, no barriers;
// A-frags read straight from L2/L3-resident XF / SG.  Tail: M_fin.
__global__ __launch_bounds__(256, 3) void k4_out(
    const _Float16* __restrict__ XF, const _Float16* __restrict__ M0H,
    const _Float16* __restrict__ SG, const _Float16* __restrict__ WTH,
    const _Float16* __restrict__ KFT, const float* __restrict__ SIG,
    const float* __restrict__ FRHO, const float* __restrict__ M0,
    float* __restrict__ out)
{
    const int tid = threadIdx.x, lane = tid & 63, w = tid >> 6;
    const int q = lane >> 4, l15 = lane & 15;

    if (blockIdx.x >= BB * NC) {  // M_fin tail: 96 WGs
        const int tw = blockIdx.x - BB * NC;
        const int b = tw / 12, sub = tw % 12;
        const int obk = sub >> 1, dh = sub & 1;
        const int o_t = obk * 64 + w * 16;
        f32x4 acc[12];
        for (int dt = 0; dt < 12; ++dt) acc[dt] = (f32x4){0.f, 0.f, 0.f, 0.f};
        for (int kd = 0; kd < 4; ++kd) {
            h8_t af = *(const h8_t*)&WTH[((size_t)b * DD + o_t + l15) * NC + kd * 32 + q * 8];
            for (int dt = 0; dt < 12; ++dt) {
                int d = dh * 192 + dt * 16 + l15;
                h8_t bf = *(const h8_t*)&KFT[((size_t)b * DD + d) * NC + kd * 32 + q * 8];
                acc[dt] = MFMA(af, bf, acc[dt], 0, 0, 0);
            }
        }
        float fr = FRHO[b];
        float* dst = out + (size_t)BB * SS * DD;
        for (int dt = 0; dt < 12; ++dt)
            for (int r = 0; r < 4; ++r) {
                int o = o_t + q * 4 + r, d = dh * 192 + dt * 16 + l15;
                dst[((size_t)b * DD + o) * DD + d] =
                    fr * (M0[(size_t)o * DD + d] + acc[dt][r]);
            }
        return;
    }

    const int b = blockIdx.x >> 7, n = blockIdx.x & 127;
    const size_t chunk_off = (size_t)(b * SS + n * CH) * DD;
    f32x4 acc[4][6];
    for (int mi = 0; mi < 4; ++mi)
        for (int nj = 0; nj < 6; ++nj) acc[mi][nj] = (f32x4){0.f, 0.f, 0.f, 0.f};

    const _Float16* __restrict__ Arow = XF + chunk_off;
    for (int kd = 0; kd < 12; ++kd) {  // term1: chunk @ M0^T
        h8_t af[4];
        for (int mi = 0; mi < 4; ++mi)
            af[mi] = *(const h8_t*)&Arow[(size_t)(mi * 16 + l15) * DD + kd * 32 + q * 8];
        h8_t bf[6];
        for (int nj = 0; nj < 6; ++nj) {
            int o = w * 96 + nj * 16 + l15;
            bf[nj] = *(const h8_t*)&M0H[(size_t)o * DD + kd * 32 + q * 8];
        }
        for (int mi = 0; mi < 4; ++mi)
            for (int nj = 0; nj < 6; ++nj)
                acc[mi][nj] = MFMA(af[mi], bf[nj], acc[mi][nj], 0, 0, 0);
    }

    const int nb = (n + 31) >> 5;
    const _Float16* __restrict__ Srow = SG + ((size_t)(b * NC + n)) * CH * NC;
    for (int kb = 0; kb < nb; ++kb) {  // + S @ WTH^T
        h8_t af[4];
        for (int mi = 0; mi < 4; ++mi)
            af[mi] = *(const h8_t*)&Srow[(mi * 16 + l15) * NC + kb * 32 + q * 8];
        h8_t bf[6];
        for (int nj = 0; nj < 6; ++nj) {
            int o = w * 96 + nj * 16 + l15;
            bf[nj] = *(const h8_t*)&WTH[((size_t)b * DD + o) * NC + kb * 32 + q * 8];
        }
        for (int mi = 0; mi < 4; ++mi)
            for (int nj = 0; nj < 6; ++nj)
                acc[mi][nj] = MFMA(af[mi], bf[nj], acc[mi][nj], 0, 0, 0);
    }

    const float sg = SIG[b * NC + n];
    for (int mi = 0; mi < 4; ++mi)
        for (int nj = 0; nj < 6; ++nj)
            for (int r = 0; r < 4; ++r) {
                int c = mi * 16 + q * 4 + r, o = w * 96 + nj * 16 + l15;
                out[chunk_off + (size_t)c * DD + o] = sg * acc[mi][nj][r];
            }
}

// ---------------------------------------------------------------- launch
extern "C" void kernel_launch(void* const* d_in, const int* in_sizes, int n_in,
                              void* d_out, int out_size, void* d_ws, size_t ws_size,
                              hipStream_t stream) {
    (void)in_sizes; (void)n_in; (void)out_size; (void)ws_size;
    const float* x         = (const float*)d_in[0];
    const float* M0        = (const float*)d_in[1];
    const float* eta_raw   = (const float*)d_in[2];
    const float* alpha_raw = (const float*)d_in[3];
    const float* gate_w    = (const float*)d_in[4];
    const float* gate_b    = (const float*)d_in[5];
    float* out = (float*)d_out;
    char* ws = (char*)d_ws;

    _Float16* XF  = (_Float16*)(ws);                 // 50,331,648
    _Float16* UF  = (_Float16*)(ws + 50331648);      //    786,432
    _Float16* KF  = (_Float16*)(ws + 51118080);      //    786,432
    _Float16* M0H = (_Float16*)(ws + 51904512);      //    294,912
    _Float16* GT  = (_Float16*)(ws + 52199424);      //    262,144
    _Float16* HT  = (_Float16*)(ws + 52461568);      //    262,144
    _Float16* V0T = (_Float16*)(ws + 52723712);      //    786,432
    _Float16* VTA = (_Float16*)(ws + 53510144);      //    786,432
    _Float16* VTB = (_Float16*)(ws + 54296576);      //    786,432
    _Float16* WTH = (_Float16*)(ws + 55083008);      //    786,432
    _Float16* KFT = (_Float16*)(ws + 55869440);      //    786,432
    _Float16* SG  = (_Float16*)(ws + 56655872);      // 16,777,216
    float*    AB  = (float*)(ws + 73433088);         //      8,192
    float*    TAB = (float*)(ws + 73441280);         //      4,096
    float*    SKK = (float*)(ws + 73445376);         //      4,096
    float*    SVP = (float*)(ws + 73449472);         //     12,288
    float*    SVVP= (float*)(ws + 73461760);         //     12,288
    float*    SIG = (float*)(ws + 73474048);         //      4,096
    float*    FRHO= (float*)(ws + 73478144);         //        256

    k1_stats<<<dim3(BB * NC), dim3(512), 0, stream>>>(
        x, M0, eta_raw, alpha_raw, gate_w, gate_b, XF, UF, KF, AB, TAB, SKK, M0H);
    k_score<<<dim3(BB * NC), dim3(256), 0, stream>>>(XF, KF, SG);
    kA<<<dim3(8 + BB * 3), dim3(256), 0, stream>>>(KF, UF, M0H, TAB, GT, HT, V0T);
    k_chain<<<dim3(BB * 3), dim3(256), 0, stream>>>(V0T, V0T, GT, VTA);
    k_chain<<<dim3(BB * 3), dim3(256), 0, stream>>>(VTA, V0T, GT, VTB);
    k_what<<<dim3(BB * 3), dim3(256), 0, stream>>>(KF, M0H, HT, VTB, SVP, SVVP);
    kC<<<dim3(56), dim3(256), 0, stream>>>(
        VTB, KF, TAB, M0, AB, SKK, SVP, SVVP, WTH, KFT, SIG, FRHO);
    k4_out<<<dim3(BB * NC + 96), dim3(256), 0, stream>>>(
        XF, M0H, SG, WTH, KFT, SIG, FRHO, M0, out);
}